// Round 2
// baseline (1128.421 us; speedup 1.0000x reference)
//
#include <hip/hip_runtime.h>
#include <hip/hip_bf16.h>

typedef float f32x4 __attribute__((ext_vector_type(4)));
typedef __bf16 bf16x8 __attribute__((ext_vector_type(8)));
typedef unsigned short u16x4 __attribute__((ext_vector_type(4)));
typedef unsigned short u16x8 __attribute__((ext_vector_type(8)));

// LDS layout (bytes). Total 51200 -> 3 blocks/CU (160K LDS).
#define SA   0          // 24576 : [64 tok][192 ch] bf16, stride 384B, XOR-swizzled. h / projout / h2 / mlpout
#define SQ   24576      // 4096  : [64 tok][32 ch] bf16, stride 64B (per-head Q)
#define SK   28672      // 4096  : per-head K, same layout
#define SVT  32768      // 4096  : per-head V^T [32 ch][64 tok], stride 128B
#define SP   36864      // 8192  : per-head P [64 q][64 k], stride 128B (wave-private rows)
#define SO   45056      // 4096  : per-head O [64 tok][32 d], stride 64B
#define SG   24576      // 24576 : overlays SQ..SO during MLP: [64 tok][192 mch] bf16
#define RED  49152      // 2048  : float[256][2] LN partials
#define SMEM_BYTES 51200

__device__ __forceinline__ int swzA(int row, int cb){ return row*384 + (cb ^ ((row&7)<<4)); }
__device__ __forceinline__ int swz64(int row, int cb){ return row*128 + (cb ^ ((row&7)<<4)); }
__device__ __forceinline__ int swz32(int row, int cb){ return row*64  + (cb ^ ((row&3)<<4)); }
__device__ __forceinline__ unsigned short f2b(float x){ return __builtin_bit_cast(unsigned short, (__bf16)x); }
__device__ __forceinline__ float b2f(unsigned short u){ return (float)__builtin_bit_cast(__bf16, u); }

// Transpose + cast weights to bf16 [N][K] so MFMA fragments are 8 contiguous k-elems.
__global__ void prep_weights(const float* __restrict__ wqkv, const float* __restrict__ wproj,
                             const float* __restrict__ wmlp1, const float* __restrict__ wmlp2,
                             unsigned short* __restrict__ ws){
  int idx = blockIdx.x*256 + threadIdx.x;
  if (idx < 110592){ int n=idx/192, k=idx%192; ws[idx] = f2b(wqkv[k*576+n]); }
  else if (idx < 147456){ int i=idx-110592; int n=i/192, k=i%192; ws[idx] = f2b(wproj[k*192+n]); }
  else if (idx < 294912){ int i=idx-147456; int n=i/192, k=i%192; ws[idx] = f2b(wmlp1[k*768+n]); }
  else if (idx < 442368){ int i=idx-294912; int n=i/768, k=i%768; ws[idx] = f2b(wmlp2[k*192+n]); }
}

__global__ void __launch_bounds__(256, 3) winblock(
    const float* __restrict__ x,
    const float* __restrict__ bqkv, const float* __restrict__ bproj,
    const float* __restrict__ ln1g, const float* __restrict__ ln1b,
    const float* __restrict__ ln2g, const float* __restrict__ ln2b,
    const float* __restrict__ bmlp1, const float* __restrict__ bmlp2,
    const unsigned short* __restrict__ wqkvT, const unsigned short* __restrict__ wprojT,
    const unsigned short* __restrict__ wmlp1T, const unsigned short* __restrict__ wmlp2T,
    float* __restrict__ out)
{
  __shared__ __align__(16) char sm[SMEM_BYTES];
  const int tid=threadIdx.x, w=tid>>6, l=tid&63, l16=l&15, lg=l>>4;
  // XCD-aware swizzle: HW assigns block b -> XCD b%8; give each XCD 512 consecutive work ids
  const int wid=(blockIdx.x&7)*512 + (blockIdx.x>>3);
  const int bb=wid>>10, wh=(wid>>5)&31, wwi=wid&31;
  const size_t imgoff=(size_t)bb*192*65536 + (size_t)(wh*8)*256 + (size_t)(wwi*8);
  const int toff=(l>>3)*256 + (l&7);   // this thread's token = l
  float* red=(float*)(sm+RED);
  const int tok16 = w*16 + l16;        // wave w owns token-tile w rows (as A/B row = lane&15)

  // ---- Phase A: load x window. t[i] = residual, channel w*48+i, token l (f32, registers) ----
  float t[48];
  #pragma unroll
  for(int i=0;i<48;++i) t[i]=x[imgoff+(size_t)(w*48+i)*65536+(size_t)toff];

  // ---- Phase B: LN1 -> sA (bf16 h) ----
  {
    float s=0.f,s2=0.f;
    #pragma unroll
    for(int i=0;i<48;++i){ s+=t[i]; s2+=t[i]*t[i]; }
    red[(w*64+l)*2]=s; red[(w*64+l)*2+1]=s2;
    __syncthreads();
    float S=0.f,S2=0.f;
    #pragma unroll
    for(int u=0;u<4;++u){ S+=red[(u*64+l)*2]; S2+=red[(u*64+l)*2+1]; }
    float mean=S*(1.f/192.f), var=S2*(1.f/192.f)-mean*mean, rstd=rsqrtf(var+1e-5f);
    #pragma unroll
    for(int ch=0;ch<6;++ch){
      u16x8 pk;
      #pragma unroll
      for(int j=0;j<8;++j){ int c=w*48+ch*8+j; pk[j]=f2b((t[ch*8+j]-mean)*rstd*ln1g[c]+ln1b[c]); }
      *(u16x8*)(sm+SA+swzA(l, w*96+ch*16))=pk;
    }
    __syncthreads();
  }

  // persistent proj accumulator: D col=tok(l16 in tile tt), row=out-ch (w*48+ct*16+lg*4+r)
  f32x4 accP[3][4];
  #pragma unroll
  for(int ct=0;ct<3;++ct){
    #pragma unroll
    for(int tt=0;tt<4;++tt) accP[ct][tt]=(f32x4){0.f,0.f,0.f,0.f};
  }

  // C.1: QKV for head h. Wave w covers token-tile w. Q,K swapped (A=W); V unswapped (A=h).
  auto c1 = [&](int h){
    f32x4 qa[2], ka[2], va[2];
    #pragma unroll
    for(int ct=0;ct<2;++ct){ qa[ct]=(f32x4){0,0,0,0}; ka[ct]=(f32x4){0,0,0,0}; va[ct]=(f32x4){0,0,0,0}; }
    #pragma unroll
    for(int ks=0;ks<6;++ks){
      const bf16x8 hh=*(const bf16x8*)(sm+SA+swzA(tok16, ks*64+lg*16));
      #pragma unroll
      for(int ct=0;ct<2;++ct){
        const bf16x8 awq=*(const bf16x8*)(wqkvT + (      h*32+ct*16+l16)*192 + ks*32+lg*8);
        qa[ct]=__builtin_amdgcn_mfma_f32_16x16x32_bf16(awq,hh,qa[ct],0,0,0);
        const bf16x8 awk=*(const bf16x8*)(wqkvT + (192 + h*32+ct*16+l16)*192 + ks*32+lg*8);
        ka[ct]=__builtin_amdgcn_mfma_f32_16x16x32_bf16(awk,hh,ka[ct],0,0,0);
        const bf16x8 awv=*(const bf16x8*)(wqkvT + (384 + h*32+ct*16+l16)*192 + ks*32+lg*8);
        va[ct]=__builtin_amdgcn_mfma_f32_16x16x32_bf16(hh,awv,va[ct],0,0,0);
      }
    }
    #pragma unroll
    for(int ct=0;ct<2;++ct){
      const f32x4 bq=*(const f32x4*)(bqkv +       h*32+ct*16+lg*4);
      const f32x4 bk=*(const f32x4*)(bqkv + 192 + h*32+ct*16+lg*4);
      u16x4 pq,pk;
      #pragma unroll
      for(int r=0;r<4;++r){ pq[r]=f2b(qa[ct][r]+bq[r]); pk[r]=f2b(ka[ct][r]+bk[r]); }
      *(u16x4*)(sm+SQ+swz32(tok16, ct*32+lg*8))=pq;   // Q[tok][ch], 4 consecutive ch
      *(u16x4*)(sm+SK+swz32(tok16, ct*32+lg*8))=pk;
      const float bv=bqkv[384 + h*32+ct*16+l16];      // V: D row(reg)=tok, col=ch
      u16x4 pv;
      #pragma unroll
      for(int r=0;r<4;++r) pv[r]=f2b(va[ct][r]+bv);
      *(u16x4*)(sm+SVT+swz64(ct*16+l16, (w*16+lg*4)*2))=pv;  // V^T[ch][tok], 4 consecutive tok
    }
  };

  c1(0);
  __syncthreads();

  #pragma unroll 1
  for(int h=0;h<6;++h){
    // ---- C.2: S^T tiles (A=K,B=Q -> D[k][q]); softmax in-register; P wave-private rows ----
    {
      const bf16x8 qb=*(const bf16x8*)(sm+SQ+swz32(tok16, lg*16));
      f32x4 sv[4];
      #pragma unroll
      for(int kt=0;kt<4;++kt){
        const bf16x8 ak=*(const bf16x8*)(sm+SK+swz32(kt*16+l16, lg*16));
        sv[kt]=__builtin_amdgcn_mfma_f32_16x16x32_bf16(ak,qb,(f32x4){0,0,0,0},0,0,0);
      }
      const float scale=0.17677669529663687f; // 1/sqrt(32)
      float mx=-3.0e38f;
      #pragma unroll
      for(int kt=0;kt<4;++kt){
        #pragma unroll
        for(int r=0;r<4;++r) mx=fmaxf(mx,sv[kt][r]);
      }
      mx=fmaxf(mx,__shfl_xor(mx,16)); mx=fmaxf(mx,__shfl_xor(mx,32));
      float sum=0.f;
      #pragma unroll
      for(int kt=0;kt<4;++kt){
        #pragma unroll
        for(int r=0;r<4;++r){ float e=__expf((sv[kt][r]-mx)*scale); sv[kt][r]=e; sum+=e; }
      }
      sum+=__shfl_xor(sum,16); sum+=__shfl_xor(sum,32);
      const float rs=1.f/sum;
      #pragma unroll
      for(int kt=0;kt<4;++kt){
        u16x4 pp;
        #pragma unroll
        for(int r=0;r<4;++r) pp[r]=f2b(sv[kt][r]*rs);
        *(u16x4*)(sm+SP+swz64(tok16, kt*32+lg*8))=pp;  // P[q][k], 4 consecutive k (own rows)
      }
    }
    // ---- C.3: O = P @ V (A=P own q-tile rows just written by this wave; B=V^T) ----
    {
      f32x4 ov[2]={(f32x4){0,0,0,0},(f32x4){0,0,0,0}};
      #pragma unroll
      for(int ks2=0;ks2<2;++ks2){
        const bf16x8 ap=*(const bf16x8*)(sm+SP+swz64(tok16, ks2*64+lg*16));
        #pragma unroll
        for(int dt=0;dt<2;++dt){
          const bf16x8 bv=*(const bf16x8*)(sm+SVT+swz64(dt*16+l16, ks2*64+lg*16));
          ov[dt]=__builtin_amdgcn_mfma_f32_16x16x32_bf16(ap,bv,ov[dt],0,0,0);
        }
      }
      #pragma unroll
      for(int dt=0;dt<2;++dt){
        #pragma unroll
        for(int r=0;r<4;++r)
          *(unsigned short*)(sm+SO+swz32(w*16+lg*4+r,(dt*16+l16)*2))=f2b(ov[dt][r]);
      }
    }
    __syncthreads();
    // ---- C.4: accP += Wproj^T-slice(A) x O(B); overlap next head's C.1 in same phase ----
    {
      bf16x8 bo[4];
      #pragma unroll
      for(int tt=0;tt<4;++tt) bo[tt]=*(const bf16x8*)(sm+SO+swz32(tt*16+l16, lg*16));
      #pragma unroll
      for(int ct=0;ct<3;++ct){
        const bf16x8 aw=*(const bf16x8*)(wprojT + (w*48+ct*16+l16)*192 + h*32+lg*8);
        #pragma unroll
        for(int tt=0;tt<4;++tt)
          accP[ct][tt]=__builtin_amdgcn_mfma_f32_16x16x32_bf16(aw,bo[tt],accP[ct][tt],0,0,0);
      }
    }
    if(h<5) c1(h+1);
    __syncthreads();
  }

  // ---- Phase D: projout(+bias) -> sA bf16 (u16x4); t += ; LN2 -> sA (h2) ----
  #pragma unroll
  for(int ct=0;ct<3;++ct){
    const f32x4 bp=*(const f32x4*)(bproj + w*48+ct*16+lg*4);
    #pragma unroll
    for(int tt=0;tt<4;++tt){
      u16x4 po;
      #pragma unroll
      for(int r=0;r<4;++r) po[r]=f2b(accP[ct][tt][r]+bp[r]);
      *(u16x4*)(sm+SA+swzA(tt*16+l16, w*96+ct*32+lg*8))=po;
    }
  }
  // same-wave write->read (wave w wrote chs w*48.., all tokens): no barrier needed
  #pragma unroll
  for(int ch=0;ch<6;++ch){
    const u16x8 pk=*(const u16x8*)(sm+SA+swzA(l, w*96+ch*16));
    #pragma unroll
    for(int j=0;j<8;++j) t[ch*8+j]+=b2f(pk[j]);
  }
  {
    float s=0.f,s2=0.f;
    #pragma unroll
    for(int i=0;i<48;++i){ s+=t[i]; s2+=t[i]*t[i]; }
    red[(w*64+l)*2]=s; red[(w*64+l)*2+1]=s2;
    __syncthreads();
    float S=0.f,S2=0.f;
    #pragma unroll
    for(int u=0;u<4;++u){ S+=red[(u*64+l)*2]; S2+=red[(u*64+l)*2+1]; }
    float mean=S*(1.f/192.f), var=S2*(1.f/192.f)-mean*mean, rstd=rsqrtf(var+1e-5f);
    #pragma unroll
    for(int ch=0;ch<6;++ch){
      u16x8 pk;
      #pragma unroll
      for(int j=0;j<8;++j){ int c=w*48+ch*8+j; pk[j]=f2b((t[ch*8+j]-mean)*rstd*ln2g[c]+ln2b[c]); }
      *(u16x8*)(sm+SA+swzA(l, w*96+ch*16))=pk;
    }
    __syncthreads();
  }

  // ---- Phase E: MLP in 4 K-chunks of 192 (A=W everywhere; u16x4 gelu writes) ----
  f32x4 accM[3][4];
  #pragma unroll
  for(int ct=0;ct<3;++ct){
    #pragma unroll
    for(int tt=0;tt<4;++tt) accM[ct][tt]=(f32x4){0.f,0.f,0.f,0.f};
  }
  #pragma unroll 1
  for(int qc=0;qc<4;++qc){
    #pragma unroll 1
    for(int ct=0;ct<3;++ct){          // per-ct to limit live VGPRs
      f32x4 g[4];
      #pragma unroll
      for(int tt=0;tt<4;++tt) g[tt]=(f32x4){0,0,0,0};
      #pragma unroll
      for(int ks=0;ks<6;++ks){
        const bf16x8 aw=*(const bf16x8*)(wmlp1T + (qc*192+w*48+ct*16+l16)*192 + ks*32+lg*8);
        #pragma unroll
        for(int tt=0;tt<4;++tt){
          const bf16x8 bh2=*(const bf16x8*)(sm+SA+swzA(tt*16+l16, ks*64+lg*16));
          g[tt]=__builtin_amdgcn_mfma_f32_16x16x32_bf16(aw,bh2,g[tt],0,0,0);
        }
      }
      const f32x4 b1=*(const f32x4*)(bmlp1 + qc*192+w*48+ct*16+lg*4);
      #pragma unroll
      for(int tt=0;tt<4;++tt){
        u16x4 pg;
        #pragma unroll
        for(int r=0;r<4;++r){
          const float xv=g[tt][r]+b1[r];
          pg[r]=f2b(0.5f*xv*(1.f+erff(xv*0.70710678118654752f)));
        }
        *(u16x4*)(sm+SG+swzA(tt*16+l16, w*96+ct*32+lg*8))=pg;
      }
    }
    __syncthreads();
    #pragma unroll
    for(int ks=0;ks<6;++ks){
      bf16x8 bg[4];
      #pragma unroll
      for(int tt=0;tt<4;++tt) bg[tt]=*(const bf16x8*)(sm+SG+swzA(tt*16+l16, ks*64+lg*16));
      #pragma unroll
      for(int ct=0;ct<3;++ct){
        const bf16x8 aw=*(const bf16x8*)(wmlp2T + (w*48+ct*16+l16)*768 + qc*192+ks*32+lg*8);
        #pragma unroll
        for(int tt=0;tt<4;++tt)
          accM[ct][tt]=__builtin_amdgcn_mfma_f32_16x16x32_bf16(aw,bg[tt],accM[ct][tt],0,0,0);
      }
    }
    __syncthreads();
  }

  // ---- Phase F: mlpout(+bias) -> sA; final residual; store ----
  #pragma unroll
  for(int ct=0;ct<3;++ct){
    const f32x4 b2=*(const f32x4*)(bmlp2 + w*48+ct*16+lg*4);
    #pragma unroll
    for(int tt=0;tt<4;++tt){
      u16x4 pm;
      #pragma unroll
      for(int r=0;r<4;++r) pm[r]=f2b(accM[ct][tt][r]+b2[r]);
      *(u16x4*)(sm+SA+swzA(tt*16+l16, w*96+ct*32+lg*8))=pm;
    }
  }
  // same-wave write->read again: no barrier needed
  #pragma unroll
  for(int ch=0;ch<6;++ch){
    const u16x8 pk=*(const u16x8*)(sm+SA+swzA(l, w*96+ch*16));
    #pragma unroll
    for(int j=0;j<8;++j)
      out[imgoff+(size_t)(w*48+ch*8+j)*65536+(size_t)toff]=t[ch*8+j]+b2f(pk[j]);
  }
}

extern "C" void kernel_launch(void* const* d_in, const int* in_sizes, int n_in,
                              void* d_out, int out_size, void* d_ws, size_t ws_size,
                              hipStream_t stream) {
  const float* x      = (const float*)d_in[0];
  const float* w_qkv  = (const float*)d_in[1];
  const float* b_qkv  = (const float*)d_in[2];
  const float* w_proj = (const float*)d_in[3];
  const float* b_proj = (const float*)d_in[4];
  const float* ln1g   = (const float*)d_in[5];
  const float* ln1b   = (const float*)d_in[6];
  const float* ln2g   = (const float*)d_in[7];
  const float* ln2b   = (const float*)d_in[8];
  const float* w_mlp1 = (const float*)d_in[9];
  const float* b_mlp1 = (const float*)d_in[10];
  const float* w_mlp2 = (const float*)d_in[11];
  const float* b_mlp2 = (const float*)d_in[12];
  unsigned short* wsu = (unsigned short*)d_ws;

  prep_weights<<<dim3(1728), dim3(256), 0, stream>>>(w_qkv, w_proj, w_mlp1, w_mlp2, wsu);
  winblock<<<dim3(4096), dim3(256), 0, stream>>>(
      x, b_qkv, b_proj, ln1g, ln1b, ln2g, ln2b, b_mlp1, b_mlp2,
      wsu, wsu+110592, wsu+147456, wsu+294912, (float*)d_out);
}